// Round 21
// baseline (1153.736 us; speedup 1.0000x reference)
//
#include <hip/hip_runtime.h>
#include <hip/hip_bf16.h>

typedef __bf16 bf16_t;
typedef __bf16 bf16x8 __attribute__((ext_vector_type(8)));
typedef __bf16 bf16x4 __attribute__((ext_vector_type(4)));
typedef float f32x4 __attribute__((ext_vector_type(4)));

#define B_ 16
#define S_ 1024
#define E_ 512
#define H_ 8
#define DH_ 64
#define L_ 6
#define F_ 2048
#define M_ (B_ * S_)   // 16384 rows

#define EXP2F(x) __builtin_amdgcn_exp2f(x)

#define GLOAD_LDS16(gsrc, ldst) \
    __builtin_amdgcn_global_load_lds((const __attribute__((address_space(1))) void*)(gsrc), \
                                     (__attribute__((address_space(3))) void*)(ldst), 16, 0, 0)

// ---------------- cast f32 -> bf16 (contiguous) ----------------
__global__ void cast_bf16_kernel(const float* __restrict__ src, bf16_t* __restrict__ dst, int n) {
    int i = (blockIdx.x * 256 + threadIdx.x) * 4;
    if (i + 3 < n) {
        f32x4 v = *(const f32x4*)&src[i];
        #pragma unroll
        for (int j = 0; j < 4; ++j) dst[i + j] = (bf16_t)v[j];
    }
}

// ------- cast + transpose: src [K,N] f32 (z-stride K*N) -> dst [N,K] bf16 (z-stride dstZ) -------
__global__ void castT_kernel(const float* __restrict__ src, bf16_t* __restrict__ dst,
                             int K, int N, size_t dstZ) {
    __shared__ bf16_t tile[32][33];
    size_t so = (size_t)blockIdx.z * K * N;
    size_t dofs = (size_t)blockIdx.z * dstZ;
    int k0 = blockIdx.y * 32, n0 = blockIdx.x * 32;
    int tx = threadIdx.x, ty = threadIdx.y;
    for (int i = ty; i < 32; i += 8)
        tile[i][tx] = (bf16_t)src[so + (size_t)(k0 + i) * N + n0 + tx];
    __syncthreads();
    for (int i = ty; i < 32; i += 8)
        dst[dofs + (size_t)(n0 + i) * K + k0 + tx] = tile[tx][i];
}

// ---------------- pack bq,bk,bv -> bqkv[L][1536] ----------------
__global__ void pack_bias_kernel(const float* __restrict__ bq, const float* __restrict__ bk,
                                 const float* __restrict__ bv, float* __restrict__ dst) {
    int i = blockIdx.x * 256 + threadIdx.x;
    if (i >= L_ * 1536) return;
    int l = i / 1536, c = i % 1536;
    float v = (c < 512) ? bq[l * 512 + c] : (c < 1024 ? bk[l * 512 + c - 512] : bv[l * 512 + c - 1024]);
    dst[i] = v;
}

// ---------------- old 128x128 GEMM (kept only for the K=64 input projection) ----------------
template<int EPI, bool RELU>
__launch_bounds__(256, 2)
__global__ void gemm_kernel(const bf16_t* __restrict__ A, const bf16_t* __restrict__ BT,
                            const float* __restrict__ bias, bf16_t* __restrict__ out16,
                            const float* __restrict__ auxf,
                            int M, int N, int K)
{
    __shared__ bf16_t As[2][128][32];
    __shared__ bf16_t Bs[2][128][32];
    const int tid = threadIdx.x;
    const int lane = tid & 63;
    const int w = tid >> 6;
    const int wm = w >> 1, wn = w & 1;
    const int m0 = blockIdx.x * 128, n0 = blockIdx.y * 128;
    const int l15 = lane & 15, lg = lane >> 4;

    const int srow = w * 32 + (lane >> 2);
    const int scol = (lane & 3) * 8;
    const bf16_t* Ab = A + (size_t)(m0 + srow) * K + scol;
    const bf16_t* Bb = BT + (size_t)(n0 + srow) * K + scol;

    f32x4 acc[4][4] = {};
    const int nt = K >> 5;

    #define STAGE(buf, t) do { \
        size_t ko_ = (size_t)(t) * 32; \
        _Pragma("unroll") \
        for (int j_ = 0; j_ < 2; ++j_) { \
            GLOAD_LDS16(Ab + (size_t)j_ * 16 * K + ko_, &As[buf][w * 32 + j_ * 16][0]); \
            GLOAD_LDS16(Bb + (size_t)j_ * 16 * K + ko_, &Bs[buf][w * 32 + j_ * 16][0]); \
        } } while (0)

    STAGE(0, 0);
    __syncthreads();
    int cur = 0;
    for (int t = 0; t < nt; ++t) {
        if (t + 1 < nt) STAGE(cur ^ 1, t + 1);
        bf16x8 af[4], bfr[4];
        #pragma unroll
        for (int m = 0; m < 4; ++m) af[m] = *(const bf16x8*)&As[cur][wm * 64 + m * 16 + l15][lg * 8];
        #pragma unroll
        for (int n = 0; n < 4; ++n) bfr[n] = *(const bf16x8*)&Bs[cur][wn * 64 + n * 16 + l15][lg * 8];
        __builtin_amdgcn_s_setprio(1);
        #pragma unroll
        for (int m = 0; m < 4; ++m)
            #pragma unroll
            for (int n = 0; n < 4; ++n)
                acc[m][n] = __builtin_amdgcn_mfma_f32_16x16x32_bf16(af[m], bfr[n], acc[m][n], 0, 0, 0);
        __builtin_amdgcn_s_setprio(0);
        __syncthreads();
        cur ^= 1;
    }
    #undef STAGE

    #pragma unroll
    for (int m = 0; m < 4; ++m) {
        #pragma unroll
        for (int n = 0; n < 4; ++n) {
            int col = n0 + wn * 64 + n * 16 + l15;
            float bv = bias[col];
            #pragma unroll
            for (int r = 0; r < 4; ++r) {
                int row = m0 + wm * 64 + m * 16 + lg * 4 + r;
                float v = acc[m][n][r] + bv;
                if (EPI == 1) v += auxf[(size_t)(row >> 10) * E_ + col];
                if (RELU) v = fmaxf(v, 0.f);
                out16[(size_t)row * N + col] = (bf16_t)v;
            }
        }
    }
}

// ---------------- gemm2: 128x256 tile, 3-buffer 2-ahead pipeline, counted vmcnt ----------------
// 72 KB LDS -> 2 blocks/CU. 1-D grid with XCD-grouped mapping: id&7 = XCD slot; each XCD owns a
// contiguous bx-chunk across ALL by -> its A-slice stays L2-resident across every N-tile.
// EPI 0: bf16(acc+bias) (opt RELU); EPI 2: +bf16 residual; EPI 4: QKV split (q/k/transposed V)
template<int EPI, bool RELU>
__launch_bounds__(512, 2)
__global__ void gemm2_kernel(const bf16_t* __restrict__ A, const bf16_t* __restrict__ BT,
                             const float* __restrict__ bias, bf16_t* __restrict__ out16,
                             const bf16_t* __restrict__ auxb,
                             bf16_t* __restrict__ outk, bf16_t* __restrict__ outv,
                             int M, int N, int K, int gy)
{
    __shared__ bf16_t AB[3][12288];
    const int tid = threadIdx.x;
    const int lane = tid & 63;
    const int w = tid >> 6;
    const int wr = w >> 2, wc = w & 3;
    const int nblk8 = (int)gridDim.x >> 3;
    const int orig = (blockIdx.x & 7) * nblk8 + (blockIdx.x >> 3);
    const int m0 = (orig / gy) * 128, n0 = (orig % gy) * 256;
    const int l15 = lane & 15, lg = lane >> 4;

    const int srow = w * 16 + (lane >> 2);
    const int scol = ((lane & 3) ^ ((lane >> 3) & 3)) * 8;
    const int cswz = (lg ^ ((l15 >> 1) & 3)) * 8;
    const bf16_t* Ab  = A  + (size_t)(m0 + srow) * K + scol;
    const bf16_t* Bb0 = BT + (size_t)(n0 + srow) * K + scol;
    const bf16_t* Bb1 = BT + (size_t)(n0 + 128 + srow) * K + scol;

    f32x4 acc[4][4] = {};
    const int nt = K >> 5;

    #define STAGE3(kt, buf) do { \
        size_t ko_ = (size_t)(kt) * 32; \
        GLOAD_LDS16(Ab  + ko_, &AB[buf][w * 512]); \
        GLOAD_LDS16(Bb0 + ko_, &AB[buf][4096 + w * 512]); \
        GLOAD_LDS16(Bb1 + ko_, &AB[buf][8192 + w * 512]); \
    } while (0)

    STAGE3(0, 0);
    STAGE3(1, 1);
    asm volatile("s_waitcnt vmcnt(3)" ::: "memory");
    __builtin_amdgcn_s_barrier();

    int bc = 0, bs = 2;
    int t = 0;
    for (; t + 2 < nt; ++t) {
        bf16x8 af[4], bf[4];
        #pragma unroll
        for (int m = 0; m < 4; ++m)
            af[m] = *(const bf16x8*)&AB[bc][(wr * 64 + m * 16 + l15) * 32 + cswz];
        #pragma unroll
        for (int n = 0; n < 4; ++n)
            bf[n] = *(const bf16x8*)&AB[bc][4096 + (wc * 64 + n * 16 + l15) * 32 + cswz];
        STAGE3(t + 2, bs);
        asm volatile("s_waitcnt vmcnt(3)" ::: "memory");
        __builtin_amdgcn_s_barrier();
        __builtin_amdgcn_s_setprio(1);
        #pragma unroll
        for (int m = 0; m < 4; ++m)
            #pragma unroll
            for (int n = 0; n < 4; ++n)
                acc[m][n] = __builtin_amdgcn_mfma_f32_16x16x32_bf16(af[m], bf[n], acc[m][n], 0, 0, 0);
        __builtin_amdgcn_s_setprio(0);
        bc = (bc == 2) ? 0 : bc + 1;
        bs = (bs == 2) ? 0 : bs + 1;
    }
    for (; t < nt; ++t) {
        bf16x8 af[4], bf[4];
        #pragma unroll
        for (int m = 0; m < 4; ++m)
            af[m] = *(const bf16x8*)&AB[bc][(wr * 64 + m * 16 + l15) * 32 + cswz];
        #pragma unroll
        for (int n = 0; n < 4; ++n)
            bf[n] = *(const bf16x8*)&AB[bc][4096 + (wc * 64 + n * 16 + l15) * 32 + cswz];
        asm volatile("s_waitcnt vmcnt(0)" ::: "memory");
        __builtin_amdgcn_s_barrier();
        __builtin_amdgcn_s_setprio(1);
        #pragma unroll
        for (int m = 0; m < 4; ++m)
            #pragma unroll
            for (int n = 0; n < 4; ++n)
                acc[m][n] = __builtin_amdgcn_mfma_f32_16x16x32_bf16(af[m], bf[n], acc[m][n], 0, 0, 0);
        __builtin_amdgcn_s_setprio(0);
        bc = (bc == 2) ? 0 : bc + 1;
    }
    #undef STAGE3

    #pragma unroll
    for (int m = 0; m < 4; ++m) {
        #pragma unroll
        for (int n = 0; n < 4; ++n) {
            int col = n0 + wc * 64 + n * 16 + l15;
            float bv = bias[col];
            if (EPI == 4 && col >= 1024) {
                int row0 = m0 + wr * 64 + m * 16 + lg * 4;
                int b = row0 >> 10, s0 = row0 & 1023;
                int vcol = col - 1024;
                bf16x4 pk;
                #pragma unroll
                for (int r = 0; r < 4; ++r) pk[r] = (bf16_t)(acc[m][n][r] + bv);
                *(bf16x4*)&outv[((size_t)(b * H_ + (vcol >> 6)) * DH_ + (vcol & 63)) * S_ + s0] = pk;
            } else {
                #pragma unroll
                for (int r = 0; r < 4; ++r) {
                    int row = m0 + wr * 64 + m * 16 + lg * 4 + r;
                    float v = acc[m][n][r] + bv;
                    if (EPI == 0) {
                        if (RELU) v = fmaxf(v, 0.f);
                        out16[(size_t)row * N + col] = (bf16_t)v;
                    } else if (EPI == 2) {
                        v += (float)auxb[(size_t)row * N + col];
                        out16[(size_t)row * N + col] = (bf16_t)v;
                    } else {  // EPI 4, q/k sections
                        if (col < 512) out16[(size_t)row * 512 + col] = (bf16_t)v;
                        else           outk[(size_t)row * 512 + (col - 512)] = (bf16_t)v;
                    }
                }
            }
        }
    }
}

// ---------------- flash attention: QBLK=256, 8 waves x 32 q-rows, fixed-offset softmax ----------------
__launch_bounds__(512, 4)
__global__ void attn_kernel(const bf16_t* __restrict__ q, const bf16_t* __restrict__ k,
                            const bf16_t* __restrict__ vt, bf16_t* __restrict__ o)
{
    const int id = blockIdx.x;
    const int rest = id >> 3;
    const int qb = rest & 3;
    const int bh = (id & 7) * 16 + (rest >> 2);
    const int b = bh >> 3, h = bh & 7;
    const int tid = threadIdx.x, lane = tid & 63, w = tid >> 6;   // 8 waves
    const int l15 = lane & 15, lg = lane >> 4;
    const int q0 = qb * 256 + w * 32;

    __shared__ bf16_t Ks[3][64 * 64];
    __shared__ bf16_t Vs[3][64 * 64];
    __shared__ char psh_all[8][4096];
    char* psh = psh_all[w];
    const int swz = (l15 & 7) << 4;

    const bf16_t* kb = k + (size_t)b * S_ * E_ + h * DH_;
    const bf16_t* vb = vt + (size_t)(b * H_ + h) * DH_ * S_;

    const int r8 = lane >> 3, c8 = lane & 7;

    #define STAGE_ATTN(buf, kk0) do { \
        int row_ = w * 8 + r8; \
        int ch_ = (c8 ^ r8) * 8; \
        GLOAD_LDS16(kb + (size_t)((kk0) + row_) * E_ + ch_, &Ks[buf][(w * 8) * 64]); \
        GLOAD_LDS16(vb + (size_t)row_ * S_ + (kk0) + ch_, &Vs[buf][(w * 8) * 64]); \
    } while (0)

    bf16x8 aq[2][2];
    #pragma unroll
    for (int m = 0; m < 2; ++m) {
        const size_t qoff = (size_t)(b * S_ + q0 + m * 16 + l15) * E_ + h * DH_;
        aq[m][0] = *(const bf16x8*)&q[qoff + lg * 8];
        aq[m][1] = *(const bf16x8*)&q[qoff + 32 + lg * 8];
    }

    float lrow[2] = {0.f, 0.f};
    f32x4 accO[2][4] = {};

    const float sc = 0.125f * 1.44269504f;
    const int c0 = (lg ^ (l15 & 7)) * 8;
    const int c1 = c0 ^ 32;

    const int NT = S_ / 64;   // 16
    STAGE_ATTN(0, 0);
    STAGE_ATTN(1, 64);
    asm volatile("s_waitcnt vmcnt(2)" ::: "memory");
    __builtin_amdgcn_s_barrier();

    int bc = 0, bs = 2;
    for (int it = 0; it < NT; ++it) {
        if (it + 2 < NT) STAGE_ATTN(bs, (it + 2) * 64);

        f32x4 sf[2][4];
        #pragma unroll
        for (int n = 0; n < 4; ++n) {
            const int r = n * 16 + l15;
            bf16x8 bk0 = *(const bf16x8*)&Ks[bc][r * 64 + c0];
            bf16x8 bk1 = *(const bf16x8*)&Ks[bc][r * 64 + c1];
            __builtin_amdgcn_s_setprio(1);
            #pragma unroll
            for (int m = 0; m < 2; ++m) {
                f32x4 s = {};
                s = __builtin_amdgcn_mfma_f32_16x16x32_bf16(bk0, aq[m][0], s, 0, 0, 0);
                s = __builtin_amdgcn_mfma_f32_16x16x32_bf16(bk1, aq[m][1], s, 0, 0, 0);
                sf[m][n] = s;
            }
            __builtin_amdgcn_s_setprio(0);
        }

        #pragma unroll
        for (int m = 0; m < 2; ++m) {
            float ps = 0.f;
            #pragma unroll
            for (int n = 0; n < 4; ++n) {
                bf16x4 pw;
                #pragma unroll
                for (int r = 0; r < 4; ++r) {
                    float pv = EXP2F(fmaf(sf[m][n][r], sc, -16.f));
                    ps += pv;
                    pw[r] = (bf16_t)pv;
                }
                *(bf16x4*)(psh + (m * 16 + l15) * 128 + ((n * 32 + lg * 8) ^ swz)) = pw;
            }
            ps += __shfl_xor(ps, 16, 64);
            ps += __shfl_xor(ps, 32, 64);
            lrow[m] += ps;
        }
        asm volatile("" ::: "memory");

        bf16x8 pa[2][2];
        #pragma unroll
        for (int m = 0; m < 2; ++m)
            #pragma unroll
            for (int kk = 0; kk < 2; ++kk)
                pa[m][kk] = *(const bf16x8*)(psh + (m * 16 + l15) * 128 + ((kk * 64 + lg * 16) ^ swz));
        bf16x8 vv[4];
        #pragma unroll
        for (int dt = 0; dt < 4; ++dt)
            vv[dt] = *(const bf16x8*)&Vs[bc][(dt * 16 + l15) * 64 + c0];
        __builtin_amdgcn_s_setprio(1);
        #pragma unroll
        for (int dt = 0; dt < 4; ++dt)
            #pragma unroll
            for (int m = 0; m < 2; ++m)
                accO[m][dt] = __builtin_amdgcn_mfma_f32_16x16x32_bf16(vv[dt], pa[m][0], accO[m][dt], 0, 0, 0);
        __builtin_amdgcn_s_setprio(0);
        #pragma unroll
        for (int dt = 0; dt < 4; ++dt)
            vv[dt] = *(const bf16x8*)&Vs[bc][(dt * 16 + l15) * 64 + c1];
        __builtin_amdgcn_s_setprio(1);
        #pragma unroll
        for (int dt = 0; dt < 4; ++dt)
            #pragma unroll
            for (int m = 0; m < 2; ++m)
                accO[m][dt] = __builtin_amdgcn_mfma_f32_16x16x32_bf16(vv[dt], pa[m][1], accO[m][dt], 0, 0, 0);
        __builtin_amdgcn_s_setprio(0);

        if (it + 1 < NT) {
            if (it + 2 < NT) asm volatile("s_waitcnt vmcnt(2)" ::: "memory");
            else             asm volatile("s_waitcnt vmcnt(0)" ::: "memory");
            __builtin_amdgcn_s_barrier();
        }
        bc = (bc == 2) ? 0 : bc + 1;
        bs = (bs == 2) ? 0 : bs + 1;
    }
    #undef STAGE_ATTN

    #pragma unroll
    for (int m = 0; m < 2; ++m) {
        float rl = 1.f / lrow[m];
        #pragma unroll
        for (int dt = 0; dt < 4; ++dt) {
            bf16x4 ov;
            #pragma unroll
            for (int r = 0; r < 4; ++r) ov[r] = (bf16_t)(accO[m][dt][r] * rl);
            *(bf16x4*)&o[(size_t)(b * S_ + q0 + m * 16 + l15) * E_ + h * DH_ + dt * 16 + lg * 4] = ov;
        }
    }
}

// ---------------- layernorm (bf16 in, bf16 out), one wave per row ----------------
__launch_bounds__(256)
__global__ void ln_kernel(const bf16_t* __restrict__ in, const float* __restrict__ g,
                          const float* __restrict__ be, bf16_t* __restrict__ out)
{
    int row = blockIdx.x * 4 + (threadIdx.x >> 6);
    int lane = threadIdx.x & 63;
    bf16x8 v = *(const bf16x8*)&in[(size_t)row * E_ + lane * 8];
    float x[8];
    #pragma unroll
    for (int j = 0; j < 8; ++j) x[j] = (float)v[j];
    float s = 0.f;
    #pragma unroll
    for (int j = 0; j < 8; ++j) s += x[j];
    #pragma unroll
    for (int off = 32; off >= 1; off >>= 1) s += __shfl_xor(s, off, 64);
    float mean = s * (1.f / E_);
    float vs = 0.f;
    #pragma unroll
    for (int j = 0; j < 8; ++j) { float d = x[j] - mean; vs += d * d; }
    #pragma unroll
    for (int off = 32; off >= 1; off >>= 1) vs += __shfl_xor(vs, off, 64);
    float rstd = rsqrtf(vs * (1.f / E_) + 1e-5f);
    bf16x8 y;
    #pragma unroll
    for (int j = 0; j < 8; ++j) {
        int col = lane * 8 + j;
        y[j] = (bf16_t)((x[j] - mean) * rstd * g[col] + be[col]);
    }
    *(bf16x8*)&out[(size_t)row * E_ + lane * 8] = y;
}

// ---------------- final: LN + [E,2] head (bf16 in), one wave per row ----------------
__launch_bounds__(256)
__global__ void final_kernel(const bf16_t* __restrict__ in, const float* __restrict__ g,
                             const float* __restrict__ be, const float* __restrict__ Wout,
                             const float* __restrict__ bout, float* __restrict__ out)
{
    int row = blockIdx.x * 4 + (threadIdx.x >> 6);
    int lane = threadIdx.x & 63;
    bf16x8 v = *(const bf16x8*)&in[(size_t)row * E_ + lane * 8];
    float x[8];
    #pragma unroll
    for (int j = 0; j < 8; ++j) x[j] = (float)v[j];
    float s = 0.f;
    #pragma unroll
    for (int j = 0; j < 8; ++j) s += x[j];
    #pragma unroll
    for (int off = 32; off >= 1; off >>= 1) s += __shfl_xor(s, off, 64);
    float mean = s * (1.f / E_);
    float vs = 0.f;
    #pragma unroll
    for (int j = 0; j < 8; ++j) { float d = x[j] - mean; vs += d * d; }
    #pragma unroll
    for (int off = 32; off >= 1; off >>= 1) vs += __shfl_xor(vs, off, 64);
    float rstd = rsqrtf(vs * (1.f / E_) + 1e-5f);
    float p0 = 0.f, p1 = 0.f;
    #pragma unroll
    for (int j = 0; j < 8; ++j) {
        int col = lane * 8 + j;
        float y = (x[j] - mean) * rstd * g[col] + be[col];
        p0 += y * Wout[col * 2 + 0];
        p1 += y * Wout[col * 2 + 1];
    }
    #pragma unroll
    for (int off = 32; off >= 1; off >>= 1) { p0 += __shfl_xor(p0, off, 64); p1 += __shfl_xor(p1, off, 64); }
    if (lane == 0) {
        out[(size_t)row * 2 + 0] = p0 + bout[0];
        out[(size_t)row * 2 + 1] = p1 + bout[1];
    }
}

extern "C" void kernel_launch(void* const* d_in, const int* in_sizes, int n_in,
                              void* d_out, int out_size, void* d_ws, size_t ws_size,
                              hipStream_t stream)
{
    (void)in_sizes; (void)n_in; (void)out_size;
    const float* x    = (const float*)d_in[0];
    const float* Win  = (const float*)d_in[1];
    const float* b_in = (const float*)d_in[2];
    const float* pe   = (const float*)d_in[3];
    const float* Wq   = (const float*)d_in[4];
    const float* bq   = (const float*)d_in[5];
    const float* Wk   = (const float*)d_in[6];
    const float* bk   = (const float*)d_in[7];
    const float* Wv   = (const float*)d_in[8];
    const float* bv   = (const float*)d_in[9];
    const float* Wo   = (const float*)d_in[10];
    const float* bo   = (const float*)d_in[11];
    const float* g1   = (const float*)d_in[12];
    const float* be1  = (const float*)d_in[13];
    const float* W1   = (const float*)d_in[14];
    const float* b1   = (const float*)d_in[15];
    const float* W2   = (const float*)d_in[16];
    const float* b2   = (const float*)d_in[17];
    const float* g2   = (const float*)d_in[18];
    const float* be2  = (const float*)d_in[19];
    const float* gf   = (const float*)d_in[20];
    const float* bef  = (const float*)d_in[21];
    const float* Wout = (const float*)d_in[22];
    const float* bout = (const float*)d_in[23];

    char* p = (char*)d_ws;
    auto take = [&](size_t bytes) { char* r = p; p += (bytes + 255) & ~(size_t)255; return r; };

    bf16_t* xb    = (bf16_t*)take((size_t)M_ * 64 * 2);
    bf16_t* WinT  = (bf16_t*)take((size_t)E_ * 64 * 2);
    bf16_t* WqkvT = (bf16_t*)take((size_t)L_ * 1536 * E_ * 2);
    bf16_t* WoT   = (bf16_t*)take((size_t)L_ * E_ * E_ * 2);
    bf16_t* W1T   = (bf16_t*)take((size_t)L_ * E_ * F_ * 2);
    bf16_t* W2T   = (bf16_t*)take((size_t)L_ * E_ * F_ * 2);
    float*  bqkv  = (float*)take((size_t)L_ * 1536 * 4);
    bf16_t* hb16  = (bf16_t*)take((size_t)M_ * E_ * 2);
    bf16_t* qb16  = (bf16_t*)take((size_t)M_ * E_ * 2);
    bf16_t* kb16  = (bf16_t*)take((size_t)M_ * E_ * 2);
    bf16_t* vtb   = (bf16_t*)take((size_t)M_ * E_ * 2);
    bf16_t* ob16  = (bf16_t*)take((size_t)M_ * E_ * 2);
    bf16_t* tb16  = (bf16_t*)take((size_t)M_ * E_ * 2);
    bf16_t* ab16  = (bf16_t*)take((size_t)M_ * E_ * 2);
    // overlay: q/k/vt/o (4 * M*E*2 == M*F*2 = 64MB, contiguous takes) are dead during the FFN
    bf16_t* f1b   = qb16;

    if ((size_t)(p - (char*)d_ws) > ws_size) return;

    cast_bf16_kernel<<<dim3(M_ * 64 / 4 / 256), dim3(256), 0, stream>>>(x, xb, M_ * 64);
    castT_kernel<<<dim3(E_ / 32, 64 / 32, 1), dim3(32, 8), 0, stream>>>(Win, WinT, 64, E_, 0);
    castT_kernel<<<dim3(E_ / 32, E_ / 32, L_), dim3(32, 8), 0, stream>>>(
        Wq, WqkvT + (size_t)0 * E_, E_, E_, (size_t)1536 * E_);
    castT_kernel<<<dim3(E_ / 32, E_ / 32, L_), dim3(32, 8), 0, stream>>>(
        Wk, WqkvT + (size_t)512 * E_, E_, E_, (size_t)1536 * E_);
    castT_kernel<<<dim3(E_ / 32, E_ / 32, L_), dim3(32, 8), 0, stream>>>(
        Wv, WqkvT + (size_t)1024 * E_, E_, E_, (size_t)1536 * E_);
    castT_kernel<<<dim3(E_ / 32, E_ / 32, L_), dim3(32, 8), 0, stream>>>(
        Wo, WoT, E_, E_, (size_t)E_ * E_);
    castT_kernel<<<dim3(F_ / 32, E_ / 32, L_), dim3(32, 8), 0, stream>>>(
        W1, W1T, E_, F_, (size_t)E_ * F_);
    castT_kernel<<<dim3(E_ / 32, F_ / 32, L_), dim3(32, 8), 0, stream>>>(
        W2, W2T, F_, E_, (size_t)E_ * F_);
    pack_bias_kernel<<<dim3((L_ * 1536 + 255) / 256), dim3(256), 0, stream>>>(bq, bk, bv, bqkv);

    gemm_kernel<1, false><<<dim3(M_ / 128, E_ / 128), dim3(256), 0, stream>>>(
        xb, WinT, b_in, hb16, pe, M_, E_, 64);

    for (int i = 0; i < L_; ++i) {
        const bf16_t* WqkvTi = WqkvT + (size_t)i * 1536 * E_;
        const bf16_t* WoTi   = WoT + (size_t)i * E_ * E_;
        const bf16_t* W1Ti   = W1T + (size_t)i * E_ * F_;
        const bf16_t* W2Ti   = W2T + (size_t)i * E_ * F_;

        gemm2_kernel<4, false><<<dim3(768), dim3(512), 0, stream>>>(
            hb16, WqkvTi, bqkv + (size_t)i * 1536, qb16, nullptr, kb16, vtb, M_, 1536, E_, 6);
        attn_kernel<<<dim3(512), dim3(512), 0, stream>>>(qb16, kb16, vtb, ob16);
        gemm2_kernel<2, false><<<dim3(256), dim3(512), 0, stream>>>(
            ob16, WoTi, bo + i * E_, tb16, hb16, nullptr, nullptr, M_, E_, E_, 2);
        ln_kernel<<<dim3(M_ / 4), dim3(256), 0, stream>>>(tb16, g1 + i * E_, be1 + i * E_, ab16);
        gemm2_kernel<0, true><<<dim3(1024), dim3(512), 0, stream>>>(
            ab16, W1Ti, b1 + i * F_, f1b, nullptr, nullptr, nullptr, M_, F_, E_, 8);
        gemm2_kernel<2, false><<<dim3(256), dim3(512), 0, stream>>>(
            f1b, W2Ti, b2 + i * E_, tb16, ab16, nullptr, nullptr, M_, E_, F_, 2);
        ln_kernel<<<dim3(M_ / 4), dim3(256), 0, stream>>>(tb16, g2 + i * E_, be2 + i * E_, hb16);
    }

    final_kernel<<<dim3(M_ / 4), dim3(256), 0, stream>>>(hb16, gf, bef, Wout, bout, (float*)d_out);
}

// Round 22
// 1147.069 us; speedup vs baseline: 1.0058x; 1.0058x over previous
//
#include <hip/hip_runtime.h>
#include <hip/hip_bf16.h>

typedef __bf16 bf16_t;
typedef __bf16 bf16x8 __attribute__((ext_vector_type(8)));
typedef __bf16 bf16x4 __attribute__((ext_vector_type(4)));
typedef float f32x4 __attribute__((ext_vector_type(4)));

#define B_ 16
#define S_ 1024
#define E_ 512
#define H_ 8
#define DH_ 64
#define L_ 6
#define F_ 2048
#define M_ (B_ * S_)   // 16384 rows

#define EXP2F(x) __builtin_amdgcn_exp2f(x)

#define GLOAD_LDS16(gsrc, ldst) \
    __builtin_amdgcn_global_load_lds((const __attribute__((address_space(1))) void*)(gsrc), \
                                     (__attribute__((address_space(3))) void*)(ldst), 16, 0, 0)

// ---------------- cast f32 -> bf16 (contiguous) ----------------
__global__ void cast_bf16_kernel(const float* __restrict__ src, bf16_t* __restrict__ dst, int n) {
    int i = (blockIdx.x * 256 + threadIdx.x) * 4;
    if (i + 3 < n) {
        f32x4 v = *(const f32x4*)&src[i];
        #pragma unroll
        for (int j = 0; j < 4; ++j) dst[i + j] = (bf16_t)v[j];
    }
}

// ------- cast + transpose: src [K,N] f32 (z-stride K*N) -> dst [N,K] bf16 (z-stride dstZ) -------
__global__ void castT_kernel(const float* __restrict__ src, bf16_t* __restrict__ dst,
                             int K, int N, size_t dstZ) {
    __shared__ bf16_t tile[32][33];
    size_t so = (size_t)blockIdx.z * K * N;
    size_t dofs = (size_t)blockIdx.z * dstZ;
    int k0 = blockIdx.y * 32, n0 = blockIdx.x * 32;
    int tx = threadIdx.x, ty = threadIdx.y;
    for (int i = ty; i < 32; i += 8)
        tile[i][tx] = (bf16_t)src[so + (size_t)(k0 + i) * N + n0 + tx];
    __syncthreads();
    for (int i = ty; i < 32; i += 8)
        dst[dofs + (size_t)(n0 + i) * K + k0 + tx] = tile[tx][i];
}

// ---- merged cast+transpose for the four ExE weights (Wq/Wk/Wv -> WqkvT rows, Wo -> WoT) ----
// blockIdx.z in [0, 4L): l = z>>2, which = z&3. Saves 3 prologue launches vs separate castT calls.
__global__ void castT_qkvo_kernel(const float* __restrict__ Wq, const float* __restrict__ Wk,
                                  const float* __restrict__ Wv, const float* __restrict__ Wo_,
                                  bf16_t* __restrict__ WqkvT, bf16_t* __restrict__ WoT) {
    __shared__ bf16_t tile[32][33];
    int z = blockIdx.z;
    int l = z >> 2, which = z & 3;
    const float* src = (which == 0) ? Wq : (which == 1) ? Wk : (which == 2) ? Wv : Wo_;
    src += (size_t)l * E_ * E_;
    bf16_t* dst = (which < 3) ? (WqkvT + (size_t)l * 1536 * E_ + (size_t)which * 512 * E_)
                              : (WoT + (size_t)l * E_ * E_);
    int k0 = blockIdx.y * 32, n0 = blockIdx.x * 32;
    int tx = threadIdx.x, ty = threadIdx.y;
    for (int i = ty; i < 32; i += 8)
        tile[i][tx] = (bf16_t)src[(size_t)(k0 + i) * E_ + n0 + tx];
    __syncthreads();
    for (int i = ty; i < 32; i += 8)
        dst[(size_t)(n0 + i) * E_ + k0 + tx] = tile[tx][i];
}

// ---------------- pack bq,bk,bv -> bqkv[L][1536] ----------------
__global__ void pack_bias_kernel(const float* __restrict__ bq, const float* __restrict__ bk,
                                 const float* __restrict__ bv, float* __restrict__ dst) {
    int i = blockIdx.x * 256 + threadIdx.x;
    if (i >= L_ * 1536) return;
    int l = i / 1536, c = i % 1536;
    float v = (c < 512) ? bq[l * 512 + c] : (c < 1024 ? bk[l * 512 + c - 512] : bv[l * 512 + c - 1024]);
    dst[i] = v;
}

// ---------------- old 128x128 GEMM (kept only for the K=64 input projection) ----------------
template<int EPI, bool RELU>
__launch_bounds__(256, 2)
__global__ void gemm_kernel(const bf16_t* __restrict__ A, const bf16_t* __restrict__ BT,
                            const float* __restrict__ bias, bf16_t* __restrict__ out16,
                            const float* __restrict__ auxf,
                            int M, int N, int K)
{
    __shared__ bf16_t As[2][128][32];
    __shared__ bf16_t Bs[2][128][32];
    const int tid = threadIdx.x;
    const int lane = tid & 63;
    const int w = tid >> 6;
    const int wm = w >> 1, wn = w & 1;
    const int m0 = blockIdx.x * 128, n0 = blockIdx.y * 128;
    const int l15 = lane & 15, lg = lane >> 4;

    const int srow = w * 32 + (lane >> 2);
    const int scol = (lane & 3) * 8;
    const bf16_t* Ab = A + (size_t)(m0 + srow) * K + scol;
    const bf16_t* Bb = BT + (size_t)(n0 + srow) * K + scol;

    f32x4 acc[4][4] = {};
    const int nt = K >> 5;

    #define STAGE(buf, t) do { \
        size_t ko_ = (size_t)(t) * 32; \
        _Pragma("unroll") \
        for (int j_ = 0; j_ < 2; ++j_) { \
            GLOAD_LDS16(Ab + (size_t)j_ * 16 * K + ko_, &As[buf][w * 32 + j_ * 16][0]); \
            GLOAD_LDS16(Bb + (size_t)j_ * 16 * K + ko_, &Bs[buf][w * 32 + j_ * 16][0]); \
        } } while (0)

    STAGE(0, 0);
    __syncthreads();
    int cur = 0;
    for (int t = 0; t < nt; ++t) {
        if (t + 1 < nt) STAGE(cur ^ 1, t + 1);
        bf16x8 af[4], bfr[4];
        #pragma unroll
        for (int m = 0; m < 4; ++m) af[m] = *(const bf16x8*)&As[cur][wm * 64 + m * 16 + l15][lg * 8];
        #pragma unroll
        for (int n = 0; n < 4; ++n) bfr[n] = *(const bf16x8*)&Bs[cur][wn * 64 + n * 16 + l15][lg * 8];
        __builtin_amdgcn_s_setprio(1);
        #pragma unroll
        for (int m = 0; m < 4; ++m)
            #pragma unroll
            for (int n = 0; n < 4; ++n)
                acc[m][n] = __builtin_amdgcn_mfma_f32_16x16x32_bf16(af[m], bfr[n], acc[m][n], 0, 0, 0);
        __builtin_amdgcn_s_setprio(0);
        __syncthreads();
        cur ^= 1;
    }
    #undef STAGE

    #pragma unroll
    for (int m = 0; m < 4; ++m) {
        #pragma unroll
        for (int n = 0; n < 4; ++n) {
            int col = n0 + wn * 64 + n * 16 + l15;
            float bv = bias[col];
            #pragma unroll
            for (int r = 0; r < 4; ++r) {
                int row = m0 + wm * 64 + m * 16 + lg * 4 + r;
                float v = acc[m][n][r] + bv;
                if (EPI == 1) v += auxf[(size_t)(row >> 10) * E_ + col];
                if (RELU) v = fmaxf(v, 0.f);
                out16[(size_t)row * N + col] = (bf16_t)v;
            }
        }
    }
}

// ---------------- gemm2: 128x256 tile, 3-buffer 2-ahead pipeline, counted vmcnt ----------------
// 72 KB LDS -> 2 blocks/CU. 1-D grid with XCD-grouped mapping: id&7 = XCD slot; each XCD owns a
// contiguous bx-chunk across ALL by -> its A-slice stays L2-resident across every N-tile.
// EPI 0: bf16(acc+bias) (opt RELU); EPI 2: +bf16 residual; EPI 4: QKV split (q/k/transposed V)
template<int EPI, bool RELU>
__launch_bounds__(512, 2)
__global__ void gemm2_kernel(const bf16_t* __restrict__ A, const bf16_t* __restrict__ BT,
                             const float* __restrict__ bias, bf16_t* __restrict__ out16,
                             const bf16_t* __restrict__ auxb,
                             bf16_t* __restrict__ outk, bf16_t* __restrict__ outv,
                             int M, int N, int K, int gy)
{
    __shared__ bf16_t AB[3][12288];
    const int tid = threadIdx.x;
    const int lane = tid & 63;
    const int w = tid >> 6;
    const int wr = w >> 2, wc = w & 3;
    const int nblk8 = (int)gridDim.x >> 3;
    const int orig = (blockIdx.x & 7) * nblk8 + (blockIdx.x >> 3);
    const int m0 = (orig / gy) * 128, n0 = (orig % gy) * 256;
    const int l15 = lane & 15, lg = lane >> 4;

    const int srow = w * 16 + (lane >> 2);
    const int scol = ((lane & 3) ^ ((lane >> 3) & 3)) * 8;
    const int cswz = (lg ^ ((l15 >> 1) & 3)) * 8;
    const bf16_t* Ab  = A  + (size_t)(m0 + srow) * K + scol;
    const bf16_t* Bb0 = BT + (size_t)(n0 + srow) * K + scol;
    const bf16_t* Bb1 = BT + (size_t)(n0 + 128 + srow) * K + scol;

    f32x4 acc[4][4] = {};
    const int nt = K >> 5;

    #define STAGE3(kt, buf) do { \
        size_t ko_ = (size_t)(kt) * 32; \
        GLOAD_LDS16(Ab  + ko_, &AB[buf][w * 512]); \
        GLOAD_LDS16(Bb0 + ko_, &AB[buf][4096 + w * 512]); \
        GLOAD_LDS16(Bb1 + ko_, &AB[buf][8192 + w * 512]); \
    } while (0)

    STAGE3(0, 0);
    STAGE3(1, 1);
    asm volatile("s_waitcnt vmcnt(3)" ::: "memory");
    __builtin_amdgcn_s_barrier();

    int bc = 0, bs = 2;
    int t = 0;
    for (; t + 2 < nt; ++t) {
        bf16x8 af[4], bf[4];
        #pragma unroll
        for (int m = 0; m < 4; ++m)
            af[m] = *(const bf16x8*)&AB[bc][(wr * 64 + m * 16 + l15) * 32 + cswz];
        #pragma unroll
        for (int n = 0; n < 4; ++n)
            bf[n] = *(const bf16x8*)&AB[bc][4096 + (wc * 64 + n * 16 + l15) * 32 + cswz];
        STAGE3(t + 2, bs);
        asm volatile("s_waitcnt vmcnt(3)" ::: "memory");
        __builtin_amdgcn_s_barrier();
        __builtin_amdgcn_s_setprio(1);
        #pragma unroll
        for (int m = 0; m < 4; ++m)
            #pragma unroll
            for (int n = 0; n < 4; ++n)
                acc[m][n] = __builtin_amdgcn_mfma_f32_16x16x32_bf16(af[m], bf[n], acc[m][n], 0, 0, 0);
        __builtin_amdgcn_s_setprio(0);
        bc = (bc == 2) ? 0 : bc + 1;
        bs = (bs == 2) ? 0 : bs + 1;
    }
    for (; t < nt; ++t) {
        bf16x8 af[4], bf[4];
        #pragma unroll
        for (int m = 0; m < 4; ++m)
            af[m] = *(const bf16x8*)&AB[bc][(wr * 64 + m * 16 + l15) * 32 + cswz];
        #pragma unroll
        for (int n = 0; n < 4; ++n)
            bf[n] = *(const bf16x8*)&AB[bc][4096 + (wc * 64 + n * 16 + l15) * 32 + cswz];
        asm volatile("s_waitcnt vmcnt(0)" ::: "memory");
        __builtin_amdgcn_s_barrier();
        __builtin_amdgcn_s_setprio(1);
        #pragma unroll
        for (int m = 0; m < 4; ++m)
            #pragma unroll
            for (int n = 0; n < 4; ++n)
                acc[m][n] = __builtin_amdgcn_mfma_f32_16x16x32_bf16(af[m], bf[n], acc[m][n], 0, 0, 0);
        __builtin_amdgcn_s_setprio(0);
        bc = (bc == 2) ? 0 : bc + 1;
    }
    #undef STAGE3

    #pragma unroll
    for (int m = 0; m < 4; ++m) {
        #pragma unroll
        for (int n = 0; n < 4; ++n) {
            int col = n0 + wc * 64 + n * 16 + l15;
            float bv = bias[col];
            if (EPI == 4 && col >= 1024) {
                int row0 = m0 + wr * 64 + m * 16 + lg * 4;
                int b = row0 >> 10, s0 = row0 & 1023;
                int vcol = col - 1024;
                bf16x4 pk;
                #pragma unroll
                for (int r = 0; r < 4; ++r) pk[r] = (bf16_t)(acc[m][n][r] + bv);
                *(bf16x4*)&outv[((size_t)(b * H_ + (vcol >> 6)) * DH_ + (vcol & 63)) * S_ + s0] = pk;
            } else {
                #pragma unroll
                for (int r = 0; r < 4; ++r) {
                    int row = m0 + wr * 64 + m * 16 + lg * 4 + r;
                    float v = acc[m][n][r] + bv;
                    if (EPI == 0) {
                        if (RELU) v = fmaxf(v, 0.f);
                        out16[(size_t)row * N + col] = (bf16_t)v;
                    } else if (EPI == 2) {
                        v += (float)auxb[(size_t)row * N + col];
                        out16[(size_t)row * N + col] = (bf16_t)v;
                    } else {  // EPI 4, q/k sections
                        if (col < 512) out16[(size_t)row * 512 + col] = (bf16_t)v;
                        else           outk[(size_t)row * 512 + (col - 512)] = (bf16_t)v;
                    }
                }
            }
        }
    }
}

// ---------------- flash attention: QBLK=256, 8 waves x 32 q-rows, fixed-offset softmax ----------------
__launch_bounds__(512, 4)
__global__ void attn_kernel(const bf16_t* __restrict__ q, const bf16_t* __restrict__ k,
                            const bf16_t* __restrict__ vt, bf16_t* __restrict__ o)
{
    const int id = blockIdx.x;
    const int rest = id >> 3;
    const int qb = rest & 3;
    const int bh = (id & 7) * 16 + (rest >> 2);
    const int b = bh >> 3, h = bh & 7;
    const int tid = threadIdx.x, lane = tid & 63, w = tid >> 6;   // 8 waves
    const int l15 = lane & 15, lg = lane >> 4;
    const int q0 = qb * 256 + w * 32;

    __shared__ bf16_t Ks[3][64 * 64];
    __shared__ bf16_t Vs[3][64 * 64];
    __shared__ char psh_all[8][4096];
    char* psh = psh_all[w];
    const int swz = (l15 & 7) << 4;

    const bf16_t* kb = k + (size_t)b * S_ * E_ + h * DH_;
    const bf16_t* vb = vt + (size_t)(b * H_ + h) * DH_ * S_;

    const int r8 = lane >> 3, c8 = lane & 7;

    #define STAGE_ATTN(buf, kk0) do { \
        int row_ = w * 8 + r8; \
        int ch_ = (c8 ^ r8) * 8; \
        GLOAD_LDS16(kb + (size_t)((kk0) + row_) * E_ + ch_, &Ks[buf][(w * 8) * 64]); \
        GLOAD_LDS16(vb + (size_t)row_ * S_ + (kk0) + ch_, &Vs[buf][(w * 8) * 64]); \
    } while (0)

    bf16x8 aq[2][2];
    #pragma unroll
    for (int m = 0; m < 2; ++m) {
        const size_t qoff = (size_t)(b * S_ + q0 + m * 16 + l15) * E_ + h * DH_;
        aq[m][0] = *(const bf16x8*)&q[qoff + lg * 8];
        aq[m][1] = *(const bf16x8*)&q[qoff + 32 + lg * 8];
    }

    float lrow[2] = {0.f, 0.f};
    f32x4 accO[2][4] = {};

    const float sc = 0.125f * 1.44269504f;
    const int c0 = (lg ^ (l15 & 7)) * 8;
    const int c1 = c0 ^ 32;

    const int NT = S_ / 64;   // 16
    STAGE_ATTN(0, 0);
    STAGE_ATTN(1, 64);
    asm volatile("s_waitcnt vmcnt(2)" ::: "memory");
    __builtin_amdgcn_s_barrier();

    int bc = 0, bs = 2;
    for (int it = 0; it < NT; ++it) {
        if (it + 2 < NT) STAGE_ATTN(bs, (it + 2) * 64);

        f32x4 sf[2][4];
        #pragma unroll
        for (int n = 0; n < 4; ++n) {
            const int r = n * 16 + l15;
            bf16x8 bk0 = *(const bf16x8*)&Ks[bc][r * 64 + c0];
            bf16x8 bk1 = *(const bf16x8*)&Ks[bc][r * 64 + c1];
            __builtin_amdgcn_s_setprio(1);
            #pragma unroll
            for (int m = 0; m < 2; ++m) {
                f32x4 s = {};
                s = __builtin_amdgcn_mfma_f32_16x16x32_bf16(bk0, aq[m][0], s, 0, 0, 0);
                s = __builtin_amdgcn_mfma_f32_16x16x32_bf16(bk1, aq[m][1], s, 0, 0, 0);
                sf[m][n] = s;
            }
            __builtin_amdgcn_s_setprio(0);
        }

        #pragma unroll
        for (int m = 0; m < 2; ++m) {
            float ps = 0.f;
            #pragma unroll
            for (int n = 0; n < 4; ++n) {
                bf16x4 pw;
                #pragma unroll
                for (int r = 0; r < 4; ++r) {
                    float pv = EXP2F(fmaf(sf[m][n][r], sc, -16.f));
                    ps += pv;
                    pw[r] = (bf16_t)pv;
                }
                *(bf16x4*)(psh + (m * 16 + l15) * 128 + ((n * 32 + lg * 8) ^ swz)) = pw;
            }
            ps += __shfl_xor(ps, 16, 64);
            ps += __shfl_xor(ps, 32, 64);
            lrow[m] += ps;
        }
        asm volatile("" ::: "memory");

        bf16x8 pa[2][2];
        #pragma unroll
        for (int m = 0; m < 2; ++m)
            #pragma unroll
            for (int kk = 0; kk < 2; ++kk)
                pa[m][kk] = *(const bf16x8*)(psh + (m * 16 + l15) * 128 + ((kk * 64 + lg * 16) ^ swz));
        bf16x8 vv[4];
        #pragma unroll
        for (int dt = 0; dt < 4; ++dt)
            vv[dt] = *(const bf16x8*)&Vs[bc][(dt * 16 + l15) * 64 + c0];
        __builtin_amdgcn_s_setprio(1);
        #pragma unroll
        for (int dt = 0; dt < 4; ++dt)
            #pragma unroll
            for (int m = 0; m < 2; ++m)
                accO[m][dt] = __builtin_amdgcn_mfma_f32_16x16x32_bf16(vv[dt], pa[m][0], accO[m][dt], 0, 0, 0);
        __builtin_amdgcn_s_setprio(0);
        #pragma unroll
        for (int dt = 0; dt < 4; ++dt)
            vv[dt] = *(const bf16x8*)&Vs[bc][(dt * 16 + l15) * 64 + c1];
        __builtin_amdgcn_s_setprio(1);
        #pragma unroll
        for (int dt = 0; dt < 4; ++dt)
            #pragma unroll
            for (int m = 0; m < 2; ++m)
                accO[m][dt] = __builtin_amdgcn_mfma_f32_16x16x32_bf16(vv[dt], pa[m][1], accO[m][dt], 0, 0, 0);
        __builtin_amdgcn_s_setprio(0);

        if (it + 1 < NT) {
            if (it + 2 < NT) asm volatile("s_waitcnt vmcnt(2)" ::: "memory");
            else             asm volatile("s_waitcnt vmcnt(0)" ::: "memory");
            __builtin_amdgcn_s_barrier();
        }
        bc = (bc == 2) ? 0 : bc + 1;
        bs = (bs == 2) ? 0 : bs + 1;
    }
    #undef STAGE_ATTN

    #pragma unroll
    for (int m = 0; m < 2; ++m) {
        float rl = 1.f / lrow[m];
        #pragma unroll
        for (int dt = 0; dt < 4; ++dt) {
            bf16x4 ov;
            #pragma unroll
            for (int r = 0; r < 4; ++r) ov[r] = (bf16_t)(accO[m][dt][r] * rl);
            *(bf16x4*)&o[(size_t)(b * S_ + q0 + m * 16 + l15) * E_ + h * DH_ + dt * 16 + lg * 4] = ov;
        }
    }
}

// ---------------- layernorm (bf16 in, bf16 out), one wave per row ----------------
__launch_bounds__(256)
__global__ void ln_kernel(const bf16_t* __restrict__ in, const float* __restrict__ g,
                          const float* __restrict__ be, bf16_t* __restrict__ out)
{
    int row = blockIdx.x * 4 + (threadIdx.x >> 6);
    int lane = threadIdx.x & 63;
    bf16x8 v = *(const bf16x8*)&in[(size_t)row * E_ + lane * 8];
    float x[8];
    #pragma unroll
    for (int j = 0; j < 8; ++j) x[j] = (float)v[j];
    float s = 0.f;
    #pragma unroll
    for (int j = 0; j < 8; ++j) s += x[j];
    #pragma unroll
    for (int off = 32; off >= 1; off >>= 1) s += __shfl_xor(s, off, 64);
    float mean = s * (1.f / E_);
    float vs = 0.f;
    #pragma unroll
    for (int j = 0; j < 8; ++j) { float d = x[j] - mean; vs += d * d; }
    #pragma unroll
    for (int off = 32; off >= 1; off >>= 1) vs += __shfl_xor(vs, off, 64);
    float rstd = rsqrtf(vs * (1.f / E_) + 1e-5f);
    bf16x8 y;
    #pragma unroll
    for (int j = 0; j < 8; ++j) {
        int col = lane * 8 + j;
        y[j] = (bf16_t)((x[j] - mean) * rstd * g[col] + be[col]);
    }
    *(bf16x8*)&out[(size_t)row * E_ + lane * 8] = y;
}

// ---------------- final: LN + [E,2] head (bf16 in), one wave per row ----------------
__launch_bounds__(256)
__global__ void final_kernel(const bf16_t* __restrict__ in, const float* __restrict__ g,
                             const float* __restrict__ be, const float* __restrict__ Wout,
                             const float* __restrict__ bout, float* __restrict__ out)
{
    int row = blockIdx.x * 4 + (threadIdx.x >> 6);
    int lane = threadIdx.x & 63;
    bf16x8 v = *(const bf16x8*)&in[(size_t)row * E_ + lane * 8];
    float x[8];
    #pragma unroll
    for (int j = 0; j < 8; ++j) x[j] = (float)v[j];
    float s = 0.f;
    #pragma unroll
    for (int j = 0; j < 8; ++j) s += x[j];
    #pragma unroll
    for (int off = 32; off >= 1; off >>= 1) s += __shfl_xor(s, off, 64);
    float mean = s * (1.f / E_);
    float vs = 0.f;
    #pragma unroll
    for (int j = 0; j < 8; ++j) { float d = x[j] - mean; vs += d * d; }
    #pragma unroll
    for (int off = 32; off >= 1; off >>= 1) vs += __shfl_xor(vs, off, 64);
    float rstd = rsqrtf(vs * (1.f / E_) + 1e-5f);
    float p0 = 0.f, p1 = 0.f;
    #pragma unroll
    for (int j = 0; j < 8; ++j) {
        int col = lane * 8 + j;
        float y = (x[j] - mean) * rstd * g[col] + be[col];
        p0 += y * Wout[col * 2 + 0];
        p1 += y * Wout[col * 2 + 1];
    }
    #pragma unroll
    for (int off = 32; off >= 1; off >>= 1) { p0 += __shfl_xor(p0, off, 64); p1 += __shfl_xor(p1, off, 64); }
    if (lane == 0) {
        out[(size_t)row * 2 + 0] = p0 + bout[0];
        out[(size_t)row * 2 + 1] = p1 + bout[1];
    }
}

extern "C" void kernel_launch(void* const* d_in, const int* in_sizes, int n_in,
                              void* d_out, int out_size, void* d_ws, size_t ws_size,
                              hipStream_t stream)
{
    (void)in_sizes; (void)n_in; (void)out_size;
    const float* x    = (const float*)d_in[0];
    const float* Win  = (const float*)d_in[1];
    const float* b_in = (const float*)d_in[2];
    const float* pe   = (const float*)d_in[3];
    const float* Wq   = (const float*)d_in[4];
    const float* bq   = (const float*)d_in[5];
    const float* Wk   = (const float*)d_in[6];
    const float* bk   = (const float*)d_in[7];
    const float* Wv   = (const float*)d_in[8];
    const float* bv   = (const float*)d_in[9];
    const float* Wo   = (const float*)d_in[10];
    const float* bo   = (const float*)d_in[11];
    const float* g1   = (const float*)d_in[12];
    const float* be1  = (const float*)d_in[13];
    const float* W1   = (const float*)d_in[14];
    const float* b1   = (const float*)d_in[15];
    const float* W2   = (const float*)d_in[16];
    const float* b2   = (const float*)d_in[17];
    const float* g2   = (const float*)d_in[18];
    const float* be2  = (const float*)d_in[19];
    const float* gf   = (const float*)d_in[20];
    const float* bef  = (const float*)d_in[21];
    const float* Wout = (const float*)d_in[22];
    const float* bout = (const float*)d_in[23];

    char* p = (char*)d_ws;
    auto take = [&](size_t bytes) { char* r = p; p += (bytes + 255) & ~(size_t)255; return r; };

    bf16_t* xb    = (bf16_t*)take((size_t)M_ * 64 * 2);
    bf16_t* WinT  = (bf16_t*)take((size_t)E_ * 64 * 2);
    bf16_t* WqkvT = (bf16_t*)take((size_t)L_ * 1536 * E_ * 2);
    bf16_t* WoT   = (bf16_t*)take((size_t)L_ * E_ * E_ * 2);
    bf16_t* W1T   = (bf16_t*)take((size_t)L_ * E_ * F_ * 2);
    bf16_t* W2T   = (bf16_t*)take((size_t)L_ * E_ * F_ * 2);
    float*  bqkv  = (float*)take((size_t)L_ * 1536 * 4);
    bf16_t* hb16  = (bf16_t*)take((size_t)M_ * E_ * 2);
    bf16_t* qb16  = (bf16_t*)take((size_t)M_ * E_ * 2);
    bf16_t* kb16  = (bf16_t*)take((size_t)M_ * E_ * 2);
    bf16_t* vtb   = (bf16_t*)take((size_t)M_ * E_ * 2);
    bf16_t* ob16  = (bf16_t*)take((size_t)M_ * E_ * 2);
    bf16_t* tb16  = (bf16_t*)take((size_t)M_ * E_ * 2);
    bf16_t* ab16  = (bf16_t*)take((size_t)M_ * E_ * 2);
    // overlay: q/k/vt/o (4 * M*E*2 == M*F*2 = 64MB, contiguous takes) are dead during the FFN
    bf16_t* f1b   = qb16;

    if ((size_t)(p - (char*)d_ws) > ws_size) return;

    cast_bf16_kernel<<<dim3(M_ * 64 / 4 / 256), dim3(256), 0, stream>>>(x, xb, M_ * 64);
    castT_kernel<<<dim3(E_ / 32, 64 / 32, 1), dim3(32, 8), 0, stream>>>(Win, WinT, 64, E_, 0);
    castT_qkvo_kernel<<<dim3(E_ / 32, E_ / 32, 4 * L_), dim3(32, 8), 0, stream>>>(
        Wq, Wk, Wv, Wo, WqkvT, WoT);
    castT_kernel<<<dim3(F_ / 32, E_ / 32, L_), dim3(32, 8), 0, stream>>>(
        W1, W1T, E_, F_, (size_t)E_ * F_);
    castT_kernel<<<dim3(E_ / 32, F_ / 32, L_), dim3(32, 8), 0, stream>>>(
        W2, W2T, F_, E_, (size_t)E_ * F_);
    pack_bias_kernel<<<dim3((L_ * 1536 + 255) / 256), dim3(256), 0, stream>>>(bq, bk, bv, bqkv);

    gemm_kernel<1, false><<<dim3(M_ / 128, E_ / 128), dim3(256), 0, stream>>>(
        xb, WinT, b_in, hb16, pe, M_, E_, 64);

    for (int i = 0; i < L_; ++i) {
        const bf16_t* WqkvTi = WqkvT + (size_t)i * 1536 * E_;
        const bf16_t* WoTi   = WoT + (size_t)i * E_ * E_;
        const bf16_t* W1Ti   = W1T + (size_t)i * E_ * F_;
        const bf16_t* W2Ti   = W2T + (size_t)i * E_ * F_;

        gemm2_kernel<4, false><<<dim3(768), dim3(512), 0, stream>>>(
            hb16, WqkvTi, bqkv + (size_t)i * 1536, qb16, nullptr, kb16, vtb, M_, 1536, E_, 6);
        attn_kernel<<<dim3(512), dim3(512), 0, stream>>>(qb16, kb16, vtb, ob16);
        gemm2_kernel<2, false><<<dim3(256), dim3(512), 0, stream>>>(
            ob16, WoTi, bo + i * E_, tb16, hb16, nullptr, nullptr, M_, E_, E_, 2);
        ln_kernel<<<dim3(M_ / 4), dim3(256), 0, stream>>>(tb16, g1 + i * E_, be1 + i * E_, ab16);
        gemm2_kernel<0, true><<<dim3(1024), dim3(512), 0, stream>>>(
            ab16, W1Ti, b1 + i * F_, f1b, nullptr, nullptr, nullptr, M_, F_, E_, 8);
        gemm2_kernel<2, false><<<dim3(256), dim3(512), 0, stream>>>(
            f1b, W2Ti, b2 + i * E_, tb16, ab16, nullptr, nullptr, M_, E_, F_, 2);
        ln_kernel<<<dim3(M_ / 4), dim3(256), 0, stream>>>(tb16, g2 + i * E_, be2 + i * E_, hb16);
    }

    final_kernel<<<dim3(M_ / 4), dim3(256), 0, stream>>>(hb16, gf, bef, Wout, bout, (float*)d_out);
}

// Round 23
// 1141.673 us; speedup vs baseline: 1.0106x; 1.0047x over previous
//
#include <hip/hip_runtime.h>
#include <hip/hip_bf16.h>

typedef __bf16 bf16_t;
typedef __bf16 bf16x8 __attribute__((ext_vector_type(8)));
typedef __bf16 bf16x4 __attribute__((ext_vector_type(4)));
typedef float f32x4 __attribute__((ext_vector_type(4)));

#define B_ 16
#define S_ 1024
#define E_ 512
#define H_ 8
#define DH_ 64
#define L_ 6
#define F_ 2048
#define M_ (B_ * S_)   // 16384 rows

#define EXP2F(x) __builtin_amdgcn_exp2f(x)

#define GLOAD_LDS16(gsrc, ldst) \
    __builtin_amdgcn_global_load_lds((const __attribute__((address_space(1))) void*)(gsrc), \
                                     (__attribute__((address_space(3))) void*)(ldst), 16, 0, 0)

// ---------------- cast f32 -> bf16 (contiguous) ----------------
__global__ void cast_bf16_kernel(const float* __restrict__ src, bf16_t* __restrict__ dst, int n) {
    int i = (blockIdx.x * 256 + threadIdx.x) * 4;
    if (i + 3 < n) {
        f32x4 v = *(const f32x4*)&src[i];
        #pragma unroll
        for (int j = 0; j < 4; ++j) dst[i + j] = (bf16_t)v[j];
    }
}

// ------- cast + transpose: src [K,N] f32 (z-stride K*N) -> dst [N,K] bf16 (z-stride dstZ) -------
__global__ void castT_kernel(const float* __restrict__ src, bf16_t* __restrict__ dst,
                             int K, int N, size_t dstZ) {
    __shared__ bf16_t tile[32][33];
    size_t so = (size_t)blockIdx.z * K * N;
    size_t dofs = (size_t)blockIdx.z * dstZ;
    int k0 = blockIdx.y * 32, n0 = blockIdx.x * 32;
    int tx = threadIdx.x, ty = threadIdx.y;
    for (int i = ty; i < 32; i += 8)
        tile[i][tx] = (bf16_t)src[so + (size_t)(k0 + i) * N + n0 + tx];
    __syncthreads();
    for (int i = ty; i < 32; i += 8)
        dst[dofs + (size_t)(n0 + i) * K + k0 + tx] = tile[tx][i];
}

// ---- merged cast+transpose for the four ExE weights (Wq/Wk/Wv -> WqkvT rows, Wo -> WoT) ----
__global__ void castT_qkvo_kernel(const float* __restrict__ Wq, const float* __restrict__ Wk,
                                  const float* __restrict__ Wv, const float* __restrict__ Wo_,
                                  bf16_t* __restrict__ WqkvT, bf16_t* __restrict__ WoT) {
    __shared__ bf16_t tile[32][33];
    int z = blockIdx.z;
    int l = z >> 2, which = z & 3;
    const float* src = (which == 0) ? Wq : (which == 1) ? Wk : (which == 2) ? Wv : Wo_;
    src += (size_t)l * E_ * E_;
    bf16_t* dst = (which < 3) ? (WqkvT + (size_t)l * 1536 * E_ + (size_t)which * 512 * E_)
                              : (WoT + (size_t)l * E_ * E_);
    int k0 = blockIdx.y * 32, n0 = blockIdx.x * 32;
    int tx = threadIdx.x, ty = threadIdx.y;
    for (int i = ty; i < 32; i += 8)
        tile[i][tx] = (bf16_t)src[(size_t)(k0 + i) * E_ + n0 + tx];
    __syncthreads();
    for (int i = ty; i < 32; i += 8)
        dst[(size_t)(n0 + i) * E_ + k0 + tx] = tile[tx][i];
}

// ---------------- pack bq,bk,bv -> bqkv[L][1536] ----------------
__global__ void pack_bias_kernel(const float* __restrict__ bq, const float* __restrict__ bk,
                                 const float* __restrict__ bv, float* __restrict__ dst) {
    int i = blockIdx.x * 256 + threadIdx.x;
    if (i >= L_ * 1536) return;
    int l = i / 1536, c = i % 1536;
    float v = (c < 512) ? bq[l * 512 + c] : (c < 1024 ? bk[l * 512 + c - 512] : bv[l * 512 + c - 1024]);
    dst[i] = v;
}

// ---------------- old 128x128 GEMM (kept only for the K=64 input projection) ----------------
template<int EPI, bool RELU>
__launch_bounds__(256, 2)
__global__ void gemm_kernel(const bf16_t* __restrict__ A, const bf16_t* __restrict__ BT,
                            const float* __restrict__ bias, bf16_t* __restrict__ out16,
                            const float* __restrict__ auxf,
                            int M, int N, int K)
{
    __shared__ bf16_t As[2][128][32];
    __shared__ bf16_t Bs[2][128][32];
    const int tid = threadIdx.x;
    const int lane = tid & 63;
    const int w = tid >> 6;
    const int wm = w >> 1, wn = w & 1;
    const int m0 = blockIdx.x * 128, n0 = blockIdx.y * 128;
    const int l15 = lane & 15, lg = lane >> 4;

    const int srow = w * 32 + (lane >> 2);
    const int scol = (lane & 3) * 8;
    const bf16_t* Ab = A + (size_t)(m0 + srow) * K + scol;
    const bf16_t* Bb = BT + (size_t)(n0 + srow) * K + scol;

    f32x4 acc[4][4] = {};
    const int nt = K >> 5;

    #define STAGE(buf, t) do { \
        size_t ko_ = (size_t)(t) * 32; \
        _Pragma("unroll") \
        for (int j_ = 0; j_ < 2; ++j_) { \
            GLOAD_LDS16(Ab + (size_t)j_ * 16 * K + ko_, &As[buf][w * 32 + j_ * 16][0]); \
            GLOAD_LDS16(Bb + (size_t)j_ * 16 * K + ko_, &Bs[buf][w * 32 + j_ * 16][0]); \
        } } while (0)

    STAGE(0, 0);
    __syncthreads();
    int cur = 0;
    for (int t = 0; t < nt; ++t) {
        if (t + 1 < nt) STAGE(cur ^ 1, t + 1);
        bf16x8 af[4], bfr[4];
        #pragma unroll
        for (int m = 0; m < 4; ++m) af[m] = *(const bf16x8*)&As[cur][wm * 64 + m * 16 + l15][lg * 8];
        #pragma unroll
        for (int n = 0; n < 4; ++n) bfr[n] = *(const bf16x8*)&Bs[cur][wn * 64 + n * 16 + l15][lg * 8];
        __builtin_amdgcn_s_setprio(1);
        #pragma unroll
        for (int m = 0; m < 4; ++m)
            #pragma unroll
            for (int n = 0; n < 4; ++n)
                acc[m][n] = __builtin_amdgcn_mfma_f32_16x16x32_bf16(af[m], bfr[n], acc[m][n], 0, 0, 0);
        __builtin_amdgcn_s_setprio(0);
        __syncthreads();
        cur ^= 1;
    }
    #undef STAGE

    #pragma unroll
    for (int m = 0; m < 4; ++m) {
        #pragma unroll
        for (int n = 0; n < 4; ++n) {
            int col = n0 + wn * 64 + n * 16 + l15;
            float bv = bias[col];
            #pragma unroll
            for (int r = 0; r < 4; ++r) {
                int row = m0 + wm * 64 + m * 16 + lg * 4 + r;
                float v = acc[m][n][r] + bv;
                if (EPI == 1) v += auxf[(size_t)(row >> 10) * E_ + col];
                if (RELU) v = fmaxf(v, 0.f);
                out16[(size_t)row * N + col] = (bf16_t)v;
            }
        }
    }
}

// ---------------- gemm2: 128x256 tile, 3-buffer 2-ahead pipeline, counted vmcnt ----------------
// 72 KB LDS -> 2 blocks/CU. 1-D grid with XCD-grouped mapping: id&7 = XCD slot; each XCD owns a
// contiguous bx-chunk across ALL by -> its A-slice stays L2-resident across every N-tile.
// EPI 0: bf16(acc+bias) (opt RELU); EPI 2: +bf16 residual; EPI 4: QKV split (q/k/transposed V)
template<int EPI, bool RELU>
__launch_bounds__(512, 2)
__global__ void gemm2_kernel(const bf16_t* __restrict__ A, const bf16_t* __restrict__ BT,
                             const float* __restrict__ bias, bf16_t* __restrict__ out16,
                             const bf16_t* __restrict__ auxb,
                             bf16_t* __restrict__ outk, bf16_t* __restrict__ outv,
                             int M, int N, int K, int gy)
{
    __shared__ bf16_t AB[3][12288];
    const int tid = threadIdx.x;
    const int lane = tid & 63;
    const int w = tid >> 6;
    const int wr = w >> 2, wc = w & 3;
    const int nblk8 = (int)gridDim.x >> 3;
    const int orig = (blockIdx.x & 7) * nblk8 + (blockIdx.x >> 3);
    const int m0 = (orig / gy) * 128, n0 = (orig % gy) * 256;
    const int l15 = lane & 15, lg = lane >> 4;

    const int srow = w * 16 + (lane >> 2);
    const int scol = ((lane & 3) ^ ((lane >> 3) & 3)) * 8;
    const int cswz = (lg ^ ((l15 >> 1) & 3)) * 8;
    const bf16_t* Ab  = A  + (size_t)(m0 + srow) * K + scol;
    const bf16_t* Bb0 = BT + (size_t)(n0 + srow) * K + scol;
    const bf16_t* Bb1 = BT + (size_t)(n0 + 128 + srow) * K + scol;

    f32x4 acc[4][4] = {};
    const int nt = K >> 5;

    #define STAGE3(kt, buf) do { \
        size_t ko_ = (size_t)(kt) * 32; \
        GLOAD_LDS16(Ab  + ko_, &AB[buf][w * 512]); \
        GLOAD_LDS16(Bb0 + ko_, &AB[buf][4096 + w * 512]); \
        GLOAD_LDS16(Bb1 + ko_, &AB[buf][8192 + w * 512]); \
    } while (0)

    STAGE3(0, 0);
    STAGE3(1, 1);
    asm volatile("s_waitcnt vmcnt(3)" ::: "memory");
    __builtin_amdgcn_s_barrier();

    int bc = 0, bs = 2;
    int t = 0;
    for (; t + 2 < nt; ++t) {
        bf16x8 af[4], bf[4];
        #pragma unroll
        for (int m = 0; m < 4; ++m)
            af[m] = *(const bf16x8*)&AB[bc][(wr * 64 + m * 16 + l15) * 32 + cswz];
        #pragma unroll
        for (int n = 0; n < 4; ++n)
            bf[n] = *(const bf16x8*)&AB[bc][4096 + (wc * 64 + n * 16 + l15) * 32 + cswz];
        STAGE3(t + 2, bs);
        asm volatile("s_waitcnt vmcnt(3)" ::: "memory");
        __builtin_amdgcn_s_barrier();
        __builtin_amdgcn_s_setprio(1);
        #pragma unroll
        for (int m = 0; m < 4; ++m)
            #pragma unroll
            for (int n = 0; n < 4; ++n)
                acc[m][n] = __builtin_amdgcn_mfma_f32_16x16x32_bf16(af[m], bf[n], acc[m][n], 0, 0, 0);
        __builtin_amdgcn_s_setprio(0);
        bc = (bc == 2) ? 0 : bc + 1;
        bs = (bs == 2) ? 0 : bs + 1;
    }
    for (; t < nt; ++t) {
        bf16x8 af[4], bf[4];
        #pragma unroll
        for (int m = 0; m < 4; ++m)
            af[m] = *(const bf16x8*)&AB[bc][(wr * 64 + m * 16 + l15) * 32 + cswz];
        #pragma unroll
        for (int n = 0; n < 4; ++n)
            bf[n] = *(const bf16x8*)&AB[bc][4096 + (wc * 64 + n * 16 + l15) * 32 + cswz];
        asm volatile("s_waitcnt vmcnt(0)" ::: "memory");
        __builtin_amdgcn_s_barrier();
        __builtin_amdgcn_s_setprio(1);
        #pragma unroll
        for (int m = 0; m < 4; ++m)
            #pragma unroll
            for (int n = 0; n < 4; ++n)
                acc[m][n] = __builtin_amdgcn_mfma_f32_16x16x32_bf16(af[m], bf[n], acc[m][n], 0, 0, 0);
        __builtin_amdgcn_s_setprio(0);
        bc = (bc == 2) ? 0 : bc + 1;
    }
    #undef STAGE3

    #pragma unroll
    for (int m = 0; m < 4; ++m) {
        #pragma unroll
        for (int n = 0; n < 4; ++n) {
            int col = n0 + wc * 64 + n * 16 + l15;
            float bv = bias[col];
            if (EPI == 4 && col >= 1024) {
                int row0 = m0 + wr * 64 + m * 16 + lg * 4;
                int b = row0 >> 10, s0 = row0 & 1023;
                int vcol = col - 1024;
                bf16x4 pk;
                #pragma unroll
                for (int r = 0; r < 4; ++r) pk[r] = (bf16_t)(acc[m][n][r] + bv);
                *(bf16x4*)&outv[((size_t)(b * H_ + (vcol >> 6)) * DH_ + (vcol & 63)) * S_ + s0] = pk;
            } else {
                #pragma unroll
                for (int r = 0; r < 4; ++r) {
                    int row = m0 + wr * 64 + m * 16 + lg * 4 + r;
                    float v = acc[m][n][r] + bv;
                    if (EPI == 0) {
                        if (RELU) v = fmaxf(v, 0.f);
                        out16[(size_t)row * N + col] = (bf16_t)v;
                    } else if (EPI == 2) {
                        v += (float)auxb[(size_t)row * N + col];
                        out16[(size_t)row * N + col] = (bf16_t)v;
                    } else {  // EPI 4, q/k sections
                        if (col < 512) out16[(size_t)row * 512 + col] = (bf16_t)v;
                        else           outk[(size_t)row * 512 + (col - 512)] = (bf16_t)v;
                    }
                }
            }
        }
    }
}

// ---------------- flash attention: QBLK=256, 8 waves x 32 q-rows, fixed-offset softmax ----------------
__launch_bounds__(512, 4)
__global__ void attn_kernel(const bf16_t* __restrict__ q, const bf16_t* __restrict__ k,
                            const bf16_t* __restrict__ vt, bf16_t* __restrict__ o)
{
    const int id = blockIdx.x;
    const int rest = id >> 3;
    const int qb = rest & 3;
    const int bh = (id & 7) * 16 + (rest >> 2);
    const int b = bh >> 3, h = bh & 7;
    const int tid = threadIdx.x, lane = tid & 63, w = tid >> 6;   // 8 waves
    const int l15 = lane & 15, lg = lane >> 4;
    const int q0 = qb * 256 + w * 32;

    __shared__ bf16_t Ks[3][64 * 64];
    __shared__ bf16_t Vs[3][64 * 64];
    __shared__ char psh_all[8][4096];
    char* psh = psh_all[w];
    const int swz = (l15 & 7) << 4;

    const bf16_t* kb = k + (size_t)b * S_ * E_ + h * DH_;
    const bf16_t* vb = vt + (size_t)(b * H_ + h) * DH_ * S_;

    const int r8 = lane >> 3, c8 = lane & 7;

    #define STAGE_ATTN(buf, kk0) do { \
        int row_ = w * 8 + r8; \
        int ch_ = (c8 ^ r8) * 8; \
        GLOAD_LDS16(kb + (size_t)((kk0) + row_) * E_ + ch_, &Ks[buf][(w * 8) * 64]); \
        GLOAD_LDS16(vb + (size_t)row_ * S_ + (kk0) + ch_, &Vs[buf][(w * 8) * 64]); \
    } while (0)

    bf16x8 aq[2][2];
    #pragma unroll
    for (int m = 0; m < 2; ++m) {
        const size_t qoff = (size_t)(b * S_ + q0 + m * 16 + l15) * E_ + h * DH_;
        aq[m][0] = *(const bf16x8*)&q[qoff + lg * 8];
        aq[m][1] = *(const bf16x8*)&q[qoff + 32 + lg * 8];
    }

    float lrow[2] = {0.f, 0.f};
    f32x4 accO[2][4] = {};

    const float sc = 0.125f * 1.44269504f;
    const int c0 = (lg ^ (l15 & 7)) * 8;
    const int c1 = c0 ^ 32;

    const int NT = S_ / 64;   // 16
    STAGE_ATTN(0, 0);
    STAGE_ATTN(1, 64);
    asm volatile("s_waitcnt vmcnt(2)" ::: "memory");
    __builtin_amdgcn_s_barrier();

    int bc = 0, bs = 2;
    for (int it = 0; it < NT; ++it) {
        if (it + 2 < NT) STAGE_ATTN(bs, (it + 2) * 64);

        f32x4 sf[2][4];
        #pragma unroll
        for (int n = 0; n < 4; ++n) {
            const int r = n * 16 + l15;
            bf16x8 bk0 = *(const bf16x8*)&Ks[bc][r * 64 + c0];
            bf16x8 bk1 = *(const bf16x8*)&Ks[bc][r * 64 + c1];
            __builtin_amdgcn_s_setprio(1);
            #pragma unroll
            for (int m = 0; m < 2; ++m) {
                f32x4 s = {};
                s = __builtin_amdgcn_mfma_f32_16x16x32_bf16(bk0, aq[m][0], s, 0, 0, 0);
                s = __builtin_amdgcn_mfma_f32_16x16x32_bf16(bk1, aq[m][1], s, 0, 0, 0);
                sf[m][n] = s;
            }
            __builtin_amdgcn_s_setprio(0);
        }

        #pragma unroll
        for (int m = 0; m < 2; ++m) {
            float ps = 0.f;
            #pragma unroll
            for (int n = 0; n < 4; ++n) {
                bf16x4 pw;
                #pragma unroll
                for (int r = 0; r < 4; ++r) {
                    float pv = EXP2F(fmaf(sf[m][n][r], sc, -16.f));
                    ps += pv;
                    pw[r] = (bf16_t)pv;
                }
                *(bf16x4*)(psh + (m * 16 + l15) * 128 + ((n * 32 + lg * 8) ^ swz)) = pw;
            }
            ps += __shfl_xor(ps, 16, 64);
            ps += __shfl_xor(ps, 32, 64);
            lrow[m] += ps;
        }
        asm volatile("" ::: "memory");

        bf16x8 pa[2][2];
        #pragma unroll
        for (int m = 0; m < 2; ++m)
            #pragma unroll
            for (int kk = 0; kk < 2; ++kk)
                pa[m][kk] = *(const bf16x8*)(psh + (m * 16 + l15) * 128 + ((kk * 64 + lg * 16) ^ swz));
        bf16x8 vv[4];
        #pragma unroll
        for (int dt = 0; dt < 4; ++dt)
            vv[dt] = *(const bf16x8*)&Vs[bc][(dt * 16 + l15) * 64 + c0];
        __builtin_amdgcn_s_setprio(1);
        #pragma unroll
        for (int dt = 0; dt < 4; ++dt)
            #pragma unroll
            for (int m = 0; m < 2; ++m)
                accO[m][dt] = __builtin_amdgcn_mfma_f32_16x16x32_bf16(vv[dt], pa[m][0], accO[m][dt], 0, 0, 0);
        __builtin_amdgcn_s_setprio(0);
        #pragma unroll
        for (int dt = 0; dt < 4; ++dt)
            vv[dt] = *(const bf16x8*)&Vs[bc][(dt * 16 + l15) * 64 + c1];
        __builtin_amdgcn_s_setprio(1);
        #pragma unroll
        for (int dt = 0; dt < 4; ++dt)
            #pragma unroll
            for (int m = 0; m < 2; ++m)
                accO[m][dt] = __builtin_amdgcn_mfma_f32_16x16x32_bf16(vv[dt], pa[m][1], accO[m][dt], 0, 0, 0);
        __builtin_amdgcn_s_setprio(0);

        if (it + 1 < NT) {
            if (it + 2 < NT) asm volatile("s_waitcnt vmcnt(2)" ::: "memory");
            else             asm volatile("s_waitcnt vmcnt(0)" ::: "memory");
            __builtin_amdgcn_s_barrier();
        }
        bc = (bc == 2) ? 0 : bc + 1;
        bs = (bs == 2) ? 0 : bs + 1;
    }
    #undef STAGE_ATTN

    #pragma unroll
    for (int m = 0; m < 2; ++m) {
        float rl = 1.f / lrow[m];
        #pragma unroll
        for (int dt = 0; dt < 4; ++dt) {
            bf16x4 ov;
            #pragma unroll
            for (int r = 0; r < 4; ++r) ov[r] = (bf16_t)(accO[m][dt][r] * rl);
            *(bf16x4*)&o[(size_t)(b * S_ + q0 + m * 16 + l15) * E_ + h * DH_ + dt * 16 + lg * 4] = ov;
        }
    }
}

// ---------------- layernorm (bf16 in, bf16 out), one wave per row ----------------
__launch_bounds__(256)
__global__ void ln_kernel(const bf16_t* __restrict__ in, const float* __restrict__ g,
                          const float* __restrict__ be, bf16_t* __restrict__ out)
{
    int row = blockIdx.x * 4 + (threadIdx.x >> 6);
    int lane = threadIdx.x & 63;
    bf16x8 v = *(const bf16x8*)&in[(size_t)row * E_ + lane * 8];
    float x[8];
    #pragma unroll
    for (int j = 0; j < 8; ++j) x[j] = (float)v[j];
    float s = 0.f;
    #pragma unroll
    for (int j = 0; j < 8; ++j) s += x[j];
    #pragma unroll
    for (int off = 32; off >= 1; off >>= 1) s += __shfl_xor(s, off, 64);
    float mean = s * (1.f / E_);
    float vs = 0.f;
    #pragma unroll
    for (int j = 0; j < 8; ++j) { float d = x[j] - mean; vs += d * d; }
    #pragma unroll
    for (int off = 32; off >= 1; off >>= 1) vs += __shfl_xor(vs, off, 64);
    float rstd = rsqrtf(vs * (1.f / E_) + 1e-5f);
    bf16x8 y;
    #pragma unroll
    for (int j = 0; j < 8; ++j) {
        int col = lane * 8 + j;
        y[j] = (bf16_t)((x[j] - mean) * rstd * g[col] + be[col]);
    }
    *(bf16x8*)&out[(size_t)row * E_ + lane * 8] = y;
}

// ---------------- final: LN + [E,2] head (bf16 in), one wave per row ----------------
__launch_bounds__(256)
__global__ void final_kernel(const bf16_t* __restrict__ in, const float* __restrict__ g,
                             const float* __restrict__ be, const float* __restrict__ Wout,
                             const float* __restrict__ bout, float* __restrict__ out)
{
    int row = blockIdx.x * 4 + (threadIdx.x >> 6);
    int lane = threadIdx.x & 63;
    bf16x8 v = *(const bf16x8*)&in[(size_t)row * E_ + lane * 8];
    float x[8];
    #pragma unroll
    for (int j = 0; j < 8; ++j) x[j] = (float)v[j];
    float s = 0.f;
    #pragma unroll
    for (int j = 0; j < 8; ++j) s += x[j];
    #pragma unroll
    for (int off = 32; off >= 1; off >>= 1) s += __shfl_xor(s, off, 64);
    float mean = s * (1.f / E_);
    float vs = 0.f;
    #pragma unroll
    for (int j = 0; j < 8; ++j) { float d = x[j] - mean; vs += d * d; }
    #pragma unroll
    for (int off = 32; off >= 1; off >>= 1) vs += __shfl_xor(vs, off, 64);
    float rstd = rsqrtf(vs * (1.f / E_) + 1e-5f);
    float p0 = 0.f, p1 = 0.f;
    #pragma unroll
    for (int j = 0; j < 8; ++j) {
        int col = lane * 8 + j;
        float y = (x[j] - mean) * rstd * g[col] + be[col];
        p0 += y * Wout[col * 2 + 0];
        p1 += y * Wout[col * 2 + 1];
    }
    #pragma unroll
    for (int off = 32; off >= 1; off >>= 1) { p0 += __shfl_xor(p0, off, 64); p1 += __shfl_xor(p1, off, 64); }
    if (lane == 0) {
        out[(size_t)row * 2 + 0] = p0 + bout[0];
        out[(size_t)row * 2 + 1] = p1 + bout[1];
    }
}

extern "C" void kernel_launch(void* const* d_in, const int* in_sizes, int n_in,
                              void* d_out, int out_size, void* d_ws, size_t ws_size,
                              hipStream_t stream)
{
    (void)in_sizes; (void)n_in; (void)out_size;
    const float* x    = (const float*)d_in[0];
    const float* Win  = (const float*)d_in[1];
    const float* b_in = (const float*)d_in[2];
    const float* pe   = (const float*)d_in[3];
    const float* Wq   = (const float*)d_in[4];
    const float* bq   = (const float*)d_in[5];
    const float* Wk   = (const float*)d_in[6];
    const float* bk   = (const float*)d_in[7];
    const float* Wv   = (const float*)d_in[8];
    const float* bv   = (const float*)d_in[9];
    const float* Wo   = (const float*)d_in[10];
    const float* bo   = (const float*)d_in[11];
    const float* g1   = (const float*)d_in[12];
    const float* be1  = (const float*)d_in[13];
    const float* W1   = (const float*)d_in[14];
    const float* b1   = (const float*)d_in[15];
    const float* W2   = (const float*)d_in[16];
    const float* b2   = (const float*)d_in[17];
    const float* g2   = (const float*)d_in[18];
    const float* be2  = (const float*)d_in[19];
    const float* gf   = (const float*)d_in[20];
    const float* bef  = (const float*)d_in[21];
    const float* Wout = (const float*)d_in[22];
    const float* bout = (const float*)d_in[23];

    char* p = (char*)d_ws;
    auto take = [&](size_t bytes) { char* r = p; p += (bytes + 255) & ~(size_t)255; return r; };

    bf16_t* xb    = (bf16_t*)take((size_t)M_ * 64 * 2);
    bf16_t* WinT  = (bf16_t*)take((size_t)E_ * 64 * 2);
    bf16_t* WqkvT = (bf16_t*)take((size_t)L_ * 1536 * E_ * 2);
    bf16_t* WoT   = (bf16_t*)take((size_t)L_ * E_ * E_ * 2);
    bf16_t* W1T   = (bf16_t*)take((size_t)L_ * E_ * F_ * 2);
    bf16_t* W2T   = (bf16_t*)take((size_t)L_ * E_ * F_ * 2);
    float*  bqkv  = (float*)take((size_t)L_ * 1536 * 4);
    bf16_t* hb16  = (bf16_t*)take((size_t)M_ * E_ * 2);
    bf16_t* qb16  = (bf16_t*)take((size_t)M_ * E_ * 2);
    bf16_t* kb16  = (bf16_t*)take((size_t)M_ * E_ * 2);
    bf16_t* vtb   = (bf16_t*)take((size_t)M_ * E_ * 2);
    bf16_t* ob16  = (bf16_t*)take((size_t)M_ * E_ * 2);
    bf16_t* tb16  = (bf16_t*)take((size_t)M_ * E_ * 2);
    bf16_t* ab16  = (bf16_t*)take((size_t)M_ * E_ * 2);
    // overlay: q/k/vt/o (4 * M*E*2 == M*F*2 = 64MB, contiguous takes) are dead during the FFN
    bf16_t* f1b   = qb16;

    if ((size_t)(p - (char*)d_ws) > ws_size) return;

    cast_bf16_kernel<<<dim3(M_ * 64 / 4 / 256), dim3(256), 0, stream>>>(x, xb, M_ * 64);
    castT_kernel<<<dim3(E_ / 32, 64 / 32, 1), dim3(32, 8), 0, stream>>>(Win, WinT, 64, E_, 0);
    castT_qkvo_kernel<<<dim3(E_ / 32, E_ / 32, 4 * L_), dim3(32, 8), 0, stream>>>(
        Wq, Wk, Wv, Wo, WqkvT, WoT);
    castT_kernel<<<dim3(F_ / 32, E_ / 32, L_), dim3(32, 8), 0, stream>>>(
        W1, W1T, E_, F_, (size_t)E_ * F_);
    castT_kernel<<<dim3(E_ / 32, F_ / 32, L_), dim3(32, 8), 0, stream>>>(
        W2, W2T, F_, E_, (size_t)E_ * F_);
    pack_bias_kernel<<<dim3((L_ * 1536 + 255) / 256), dim3(256), 0, stream>>>(bq, bk, bv, bqkv);

    gemm_kernel<1, false><<<dim3(M_ / 128, E_ / 128), dim3(256), 0, stream>>>(
        xb, WinT, b_in, hb16, pe, M_, E_, 64);

    for (int i = 0; i < L_; ++i) {
        const bf16_t* WqkvTi = WqkvT + (size_t)i * 1536 * E_;
        const bf16_t* WoTi   = WoT + (size_t)i * E_ * E_;
        const bf16_t* W1Ti   = W1T + (size_t)i * E_ * F_;
        const bf16_t* W2Ti   = W2T + (size_t)i * E_ * F_;

        gemm2_kernel<4, false><<<dim3(768), dim3(512), 0, stream>>>(
            hb16, WqkvTi, bqkv + (size_t)i * 1536, qb16, nullptr, kb16, vtb, M_, 1536, E_, 6);
        attn_kernel<<<dim3(512), dim3(512), 0, stream>>>(qb16, kb16, vtb, ob16);
        gemm2_kernel<2, false><<<dim3(256), dim3(512), 0, stream>>>(
            ob16, WoTi, bo + i * E_, tb16, hb16, nullptr, nullptr, M_, E_, E_, 2);
        ln_kernel<<<dim3(M_ / 4), dim3(256), 0, stream>>>(tb16, g1 + i * E_, be1 + i * E_, ab16);
        gemm2_kernel<0, true><<<dim3(1024), dim3(512), 0, stream>>>(
            ab16, W1Ti, b1 + i * F_, f1b, nullptr, nullptr, nullptr, M_, F_, E_, 8);
        gemm2_kernel<2, false><<<dim3(256), dim3(512), 0, stream>>>(
            f1b, W2Ti, b2 + i * E_, tb16, ab16, nullptr, nullptr, M_, E_, F_, 2);
        ln_kernel<<<dim3(M_ / 4), dim3(256), 0, stream>>>(tb16, g2 + i * E_, be2 + i * E_, hb16);
    }

    final_kernel<<<dim3(M_ / 4), dim3(256), 0, stream>>>(hb16, gf, bef, Wout, bout, (float*)d_out);
}